// Round 3
// baseline (2517.543 us; speedup 1.0000x reference)
//
#include <hip/hip_runtime.h>
#include <cstdint>
#include <cstddef>

// Problem constants
#define L_   8
#define B_   2
#define T_   1024
#define C_   1024
#define H_   16
#define DH_  64
#define DFF_ 4096
#define M_   2048  // B_*T_

typedef __attribute__((ext_vector_type(4))) float f32x4;
typedef __attribute__((ext_vector_type(8))) short short8_t;
typedef __attribute__((ext_vector_type(8))) __bf16 bf16x8_t;
typedef __attribute__((ext_vector_type(4))) unsigned short ushort4_t;

__device__ __forceinline__ float bf2f(unsigned short u) {
  unsigned int i = ((unsigned int)u) << 16;
  return __builtin_bit_cast(float, i);
}
__device__ __forceinline__ unsigned short f2bf(float f) {
  unsigned int u = __builtin_bit_cast(unsigned int, f);
  u += 0x7fff + ((u >> 16) & 1);   // RNE
  return (unsigned short)(u >> 16);
}
__device__ __forceinline__ f32x4 mfma16x16x32(short8_t a, short8_t b, f32x4 c) {
  return __builtin_amdgcn_mfma_f32_16x16x32_bf16(
      __builtin_bit_cast(bf16x8_t, a), __builtin_bit_cast(bf16x8_t, b), c, 0, 0, 0);
}
__device__ __forceinline__ void async_copy16(const void* g, void* l) {
  __builtin_amdgcn_global_load_lds(
      (const __attribute__((address_space(1))) unsigned int*)g,
      (__attribute__((address_space(3))) unsigned int*)l, 16, 0, 0);
}

// ---------------------------------------------------------------------------
// LayerNorm: one block per row (C=1024, 256 threads -> 1 float4/thread)
// OUTF32=0: write bf16 (GEMM input); OUTF32=1: write f32 (final output)
// ---------------------------------------------------------------------------
template<int OUTF32>
__global__ __launch_bounds__(256) void ln_k(const float* __restrict__ X,
                                            const float* __restrict__ gam,
                                            const float* __restrict__ bet,
                                            void* __restrict__ out) {
  const int row = blockIdx.x;
  const int tid = threadIdx.x;
  const int lane = tid & 63, w = tid >> 6;
  const float4 v = ((const float4*)(X + (size_t)row * C_))[tid];
  float sum = v.x + v.y + v.z + v.w;
  float sq  = v.x*v.x + v.y*v.y + v.z*v.z + v.w*v.w;
#pragma unroll
  for (int d = 1; d < 64; d <<= 1) {
    sum += __shfl_xor(sum, d, 64);
    sq  += __shfl_xor(sq,  d, 64);
  }
  __shared__ float red[8];
  if (lane == 0) { red[w] = sum; red[4 + w] = sq; }
  __syncthreads();
  sum = red[0] + red[1] + red[2] + red[3];
  sq  = red[4] + red[5] + red[6] + red[7];
  const float mean = sum * (1.0f / C_);
  const float var  = sq * (1.0f / C_) - mean * mean;
  const float inv  = rsqrtf(var + 1e-5f);
  const int col = tid * 4;
  const float xs[4] = { v.x, v.y, v.z, v.w };
  if (OUTF32) {
    float4 ov;
    ov.x = (xs[0]-mean)*inv*gam[col+0] + bet[col+0];
    ov.y = (xs[1]-mean)*inv*gam[col+1] + bet[col+1];
    ov.z = (xs[2]-mean)*inv*gam[col+2] + bet[col+2];
    ov.w = (xs[3]-mean)*inv*gam[col+3] + bet[col+3];
    ((float4*)((float*)out + (size_t)row * C_))[tid] = ov;
  } else {
    ushort4_t ov;
#pragma unroll
    for (int i = 0; i < 4; ++i)
      ov[i] = f2bf((xs[i]-mean)*inv*gam[col+i] + bet[col+i]);
    *(ushort4_t*)((unsigned short*)out + (size_t)row * C_ + col) = ov;
  }
}

// ---------------------------------------------------------------------------
// Transpose + f32->bf16: W (R x Cc) -> Wt (Cc x R), 32x32 LDS tiles
// ---------------------------------------------------------------------------
__global__ __launch_bounds__(256) void transpose_bf(const float* __restrict__ W,
                                                    unsigned short* __restrict__ Wt,
                                                    int R, int Cc) {
  __shared__ float tile[32][33];
  const int c0 = blockIdx.x * 32, r0 = blockIdx.y * 32;
  const int tx = threadIdx.x & 31, ty = threadIdx.x >> 5;  // ty in 0..7
#pragma unroll
  for (int i = 0; i < 4; ++i)
    tile[ty + 8*i][tx] = W[(size_t)(r0 + ty + 8*i) * Cc + c0 + tx];
  __syncthreads();
#pragma unroll
  for (int i = 0; i < 4; ++i)
    Wt[(size_t)(c0 + ty + 8*i) * R + r0 + tx] = f2bf(tile[tx][ty + 8*i]);
}

// ---------------------------------------------------------------------------
// GEMM: C[M,N] = A[M,K] (bf16, row-major) . Bt[N,K] (bf16, row-major = W^T)
// 128x128 tile, BK=32, 4 waves of 64x64, mfma_f32_16x16x32_bf16.
// EPI 0: QKV  (N=3072): +bias{q,k,v}; q,k -> bf16 (B,T,C); v -> bf16 (B,H,DH,T)
// EPI 1: +bias0, +resid (f32), write f32
// EPI 2: +bias0, exact GELU, write bf16
// ---------------------------------------------------------------------------
template<int EPI>
__global__ __launch_bounds__(256) void gemm_bt(
    const unsigned short* __restrict__ A,
    const unsigned short* __restrict__ Bt,
    const float* __restrict__ bias0,
    const float* __restrict__ bias1,
    const float* __restrict__ bias2,
    const float* __restrict__ resid,
    void* __restrict__ out0, void* __restrict__ out1, void* __restrict__ out2,
    int M, int N, int K) {
  __shared__ __align__(16) unsigned short As[128 * 32];
  __shared__ __align__(16) unsigned short Bs[128 * 32];
  const int tid = threadIdx.x;
  const int lane = tid & 63;
  const int w = tid >> 6;
  const int ln15 = lane & 15, lg = lane >> 4;
  const int row0 = blockIdx.y * 128, col0 = blockIdx.x * 128;
  const int wr = w >> 1, wc = w & 1;

  f32x4 acc[4][4] = {};

  // staging: chunk c = i*256 + tid covers LDS bytes [c*16, c*16+16)
  // = element row (c>>2), element col (c&3)*8 of the 128x32 bf16 tile.
  const int r0s = tid >> 2,         cc0 = (tid & 3) * 8;
  const int r1s = (256 + tid) >> 2, cc1 = (tid & 3) * 8;  // (256+tid)&3 == tid&3

  for (int kt = 0; kt < K; kt += 32) {
    async_copy16(A  + (size_t)(row0 + r0s) * K + kt + cc0, (char*)As + ((size_t)w * 64) * 16);
    async_copy16(A  + (size_t)(row0 + r1s) * K + kt + cc1, (char*)As + ((size_t)(256 + w * 64)) * 16);
    async_copy16(Bt + (size_t)(col0 + r0s) * K + kt + cc0, (char*)Bs + ((size_t)w * 64) * 16);
    async_copy16(Bt + (size_t)(col0 + r1s) * K + kt + cc1, (char*)Bs + ((size_t)(256 + w * 64)) * 16);
    __syncthreads();
    short8_t af[4], bfr[4];
#pragma unroll
    for (int m = 0; m < 4; ++m)
      af[m] = *(const short8_t*)(As + (wr*64 + m*16 + ln15) * 32 + lg * 8);
#pragma unroll
    for (int n = 0; n < 4; ++n)
      bfr[n] = *(const short8_t*)(Bs + (wc*64 + n*16 + ln15) * 32 + lg * 8);
#pragma unroll
    for (int m = 0; m < 4; ++m)
#pragma unroll
      for (int n = 0; n < 4; ++n)
        acc[m][n] = mfma16x16x32(af[m], bfr[n], acc[m][n]);
    __syncthreads();
  }

#pragma unroll
  for (int m = 0; m < 4; ++m) {
#pragma unroll
    for (int n = 0; n < 4; ++n) {
#pragma unroll
      for (int r = 0; r < 4; ++r) {
        const int rg = row0 + wr*64 + m*16 + lg*4 + r;
        const int cg = col0 + wc*64 + n*16 + ln15;
        float v = acc[m][n][r];
        if (EPI == 0) {
          if (cg < 1024) {
            v += bias0[cg];
            ((unsigned short*)out0)[(size_t)rg * C_ + cg] = f2bf(v);
          } else if (cg < 2048) {
            v += bias1[cg - 1024];
            ((unsigned short*)out1)[(size_t)rg * C_ + (cg - 1024)] = f2bf(v);
          } else {
            const int ch = cg - 2048;
            v += bias2[ch];
            const int hh = ch >> 6, dh = ch & 63;
            const int bb = rg >> 10, t = rg & 1023;
            // Vt layout: (B,H,DH,T)
            ((unsigned short*)out2)[(((size_t)(bb * H_ + hh) * DH_ + dh) << 10) + t] = f2bf(v);
          }
        } else if (EPI == 1) {
          v += bias0[cg];
          ((float*)out0)[(size_t)rg * N + cg] = resid[(size_t)rg * N + cg] + v;
        } else {
          v += bias0[cg];
          v = 0.5f * v * (1.0f + erff(v * 0.70710678118654752f));
          ((unsigned short*)out0)[(size_t)rg * N + cg] = f2bf(v);
        }
      }
    }
  }
}

// ---------------------------------------------------------------------------
// RoPE in-place on bf16 q or k, (B,T,C) layout; pair = channels (2j, 2j+1)
// grid: (B*T*C/2/256, 2); blockIdx.y selects q vs k
// ---------------------------------------------------------------------------
__global__ __launch_bounds__(256) void rope_k(unsigned short* __restrict__ Q,
                                              unsigned short* __restrict__ Kb) {
  const size_t p = (size_t)blockIdx.x * 256 + threadIdx.x;  // pair index
  unsigned short* ptr = blockIdx.y ? Kb : Q;
  const int cpair = (int)(p & 511);          // C/2 = 512 pairs per row
  const int t = (int)((p >> 9) & 1023);
  const int j = cpair & 31;                  // DH/2 = 32 pairs per head
  // theta^{-2j/DH} = exp(-j * ln(10000)/32)
  const float ang = (float)t * expf((float)j * -0.28782313662425572f);
  float cs, sn;
  sincosf(ang, &sn, &cs);
  unsigned int u = *(unsigned int*)(ptr + 2 * p);
  const float x0 = bf2f((unsigned short)(u & 0xffff));
  const float x1 = bf2f((unsigned short)(u >> 16));
  const float o0 = x0 * cs - x1 * sn;
  const float o1 = x0 * sn + x1 * cs;
  *(unsigned int*)(ptr + 2 * p) = (unsigned int)f2bf(o0) | ((unsigned int)f2bf(o1) << 16);
}

// ---------------------------------------------------------------------------
// Flash attention: grid (T/64, B*H), 256 threads (4 waves, 16 q-rows each).
// Q,K bf16 (B,T,C); Vt bf16 (B,H,DH,T); Y bf16 (B,T,C). Causal, scale 1/8.
// ---------------------------------------------------------------------------
__global__ __launch_bounds__(256) void attn_k(const unsigned short* __restrict__ Q,
                                              const unsigned short* __restrict__ Kb,
                                              const unsigned short* __restrict__ Vt,
                                              unsigned short* __restrict__ Y) {
  __shared__ __align__(16) unsigned short P[64 * 64];
  const int tid = threadIdx.x, lane = tid & 63, w = tid >> 6;
  const int ln15 = lane & 15, lg = lane >> 4;
  const int qb = blockIdx.x;
  const int bh = blockIdx.y;
  const int b = bh >> 4, h = bh & 15;
  const int q0 = qb * 64;

  // Q A-fragments (row = lane&15 => q row, k = c*32 + (lane>>4)*8)
  short8_t aq[2];
  const int qrow = q0 + w * 16 + ln15;
#pragma unroll
  for (int c = 0; c < 2; ++c)
    aq[c] = *(const short8_t*)(Q + ((size_t)(b * T_ + qrow)) * C_ + h * DH_ + c * 32 + lg * 8);

  float m_run[4], l_run[4];
  f32x4 o[4] = {};
#pragma unroll
  for (int r = 0; r < 4; ++r) { m_run[r] = -1e30f; l_run[r] = 0.0f; }

  const int rowg0 = q0 + w * 16 + lg * 4;   // this thread's q rows: rowg0 + r

  for (int kb = 0; kb <= qb; ++kb) {
    // S = Q K^T  (16 q-rows x 64 keys per wave)
    f32x4 s[4] = {};
#pragma unroll
    for (int n = 0; n < 4; ++n) {
#pragma unroll
      for (int c = 0; c < 2; ++c) {
        const short8_t bk = *(const short8_t*)(Kb +
            ((size_t)(b * T_ + kb * 64 + n * 16 + ln15)) * C_ + h * DH_ + c * 32 + lg * 8);
        s[n] = mfma16x16x32(aq[c], bk, s[n]);
      }
    }
    const bool diag = (kb == qb);
    float mx[4];
#pragma unroll
    for (int r = 0; r < 4; ++r) {
      float mr = -1e30f;
#pragma unroll
      for (int n = 0; n < 4; ++n) {
        float v = s[n][r] * 0.125f;
        if (diag && (kb * 64 + n * 16 + ln15) > (rowg0 + r)) v = -1e30f;
        s[n][r] = v;
        mr = fmaxf(mr, v);
      }
      mx[r] = mr;
    }
    // row-max across the 16 lanes holding this row's keys
#pragma unroll
    for (int d = 1; d < 16; d <<= 1)
#pragma unroll
      for (int r = 0; r < 4; ++r) mx[r] = fmaxf(mx[r], __shfl_xor(mx[r], d, 64));

#pragma unroll
    for (int r = 0; r < 4; ++r) {
      const float mn = fmaxf(m_run[r], mx[r]);
      const float sc = expf(m_run[r] - mn);
      m_run[r] = mn;
      float rs = 0.0f;
#pragma unroll
      for (int n = 0; n < 4; ++n) {
        const float pv = expf(s[n][r] - mn);
        s[n][r] = pv;
        rs += pv;
      }
#pragma unroll
      for (int d = 1; d < 16; d <<= 1) rs += __shfl_xor(rs, d, 64);
      l_run[r] = l_run[r] * sc + rs;
#pragma unroll
      for (int n = 0; n < 4; ++n) o[n][r] *= sc;   // scale only row-component r
    }
    // write P (bf16) to LDS: P[qlocal][key]
#pragma unroll
    for (int r = 0; r < 4; ++r)
#pragma unroll
      for (int n = 0; n < 4; ++n)
        P[(w * 16 + lg * 4 + r) * 64 + n * 16 + ln15] = f2bf(s[n][r]);
    __syncthreads();
    // O += P V   (A = P rows = q, k = key; B rows of Vt = dh cols)
#pragma unroll
    for (int c = 0; c < 2; ++c) {
      const short8_t pa = *(const short8_t*)(P + (w * 16 + ln15) * 64 + c * 32 + lg * 8);
#pragma unroll
      for (int n = 0; n < 4; ++n) {
        const short8_t vb = *(const short8_t*)(Vt +
            ((size_t)(bh * DH_ + n * 16 + ln15)) * T_ + kb * 64 + c * 32 + lg * 8);
        o[n] = mfma16x16x32(pa, vb, o[n]);
      }
    }
    __syncthreads();
  }
#pragma unroll
  for (int n = 0; n < 4; ++n)
#pragma unroll
    for (int r = 0; r < 4; ++r) {
      const float val = o[n][r] / l_run[r];
      const int rg = rowg0 + r;
      Y[((size_t)(b * T_ + rg)) * C_ + h * DH_ + n * 16 + ln15] = f2bf(val);
    }
}

// ---------------------------------------------------------------------------
extern "C" void kernel_launch(void* const* d_in, const int* in_sizes, int n_in,
                              void* d_out, int out_size, void* d_ws, size_t ws_size,
                              hipStream_t stream) {
  const float* x    = (const float*)d_in[0];
  const float* Wq   = (const float*)d_in[1];
  const float* bq   = (const float*)d_in[2];
  const float* Wk   = (const float*)d_in[3];
  const float* bk   = (const float*)d_in[4];
  const float* Wv   = (const float*)d_in[5];
  const float* bv   = (const float*)d_in[6];
  const float* Wo   = (const float*)d_in[7];
  const float* bo   = (const float*)d_in[8];
  const float* ln1s = (const float*)d_in[9];
  const float* ln1b = (const float*)d_in[10];
  const float* ln2s = (const float*)d_in[11];
  const float* ln2b = (const float*)d_in[12];
  const float* W1   = (const float*)d_in[13];
  const float* b1   = (const float*)d_in[14];
  const float* W2   = (const float*)d_in[15];
  const float* b2   = (const float*)d_in[16];
  const float* lnfs = (const float*)d_in[17];
  const float* lnfb = (const float*)d_in[18];

  const size_t MB = (size_t)1 << 20;
  char* ws = (char*)d_ws;
  float*          h      = (float*)(ws + 0);              //  8 MB (B,T,C) f32
  unsigned short* a_bf   = (unsigned short*)(ws + 8*MB);  //  4 MB
  unsigned short* q_bf   = (unsigned short*)(ws + 12*MB); //  4 MB
  unsigned short* k_bf   = (unsigned short*)(ws + 16*MB); //  4 MB
  unsigned short* vt_bf  = (unsigned short*)(ws + 20*MB); //  4 MB (B,H,DH,T)
  unsigned short* y_bf   = (unsigned short*)(ws + 24*MB); //  4 MB
  unsigned short* mid_bf = (unsigned short*)(ws + 28*MB); // 16 MB (M,DFF)
  unsigned short* wt_bf  = (unsigned short*)(ws + 44*MB); //  8 MB

  hipMemcpyAsync(h, x, (size_t)M_ * C_ * sizeof(float), hipMemcpyDeviceToDevice, stream);

  for (int l = 0; l < L_; ++l) {
    const size_t wOff = (size_t)l * C_ * C_;
    const size_t fOff = (size_t)l * C_ * DFF_;
    // LN1 -> a_bf
    ln_k<0><<<M_, 256, 0, stream>>>(h, ln1s + l*C_, ln1b + l*C_, a_bf);
    // W^T for q,k,v (concatenated 3072 x 1024)
    transpose_bf<<<dim3(32, 32), 256, 0, stream>>>(Wq + wOff, wt_bf,           C_, C_);
    transpose_bf<<<dim3(32, 32), 256, 0, stream>>>(Wk + wOff, wt_bf + C_*C_,   C_, C_);
    transpose_bf<<<dim3(32, 32), 256, 0, stream>>>(Wv + wOff, wt_bf + 2*C_*C_, C_, C_);
    // fused QKV GEMM
    gemm_bt<0><<<dim3(24, 16), 256, 0, stream>>>(a_bf, wt_bf,
        bq + l*C_, bk + l*C_, bv + l*C_, nullptr, q_bf, k_bf, vt_bf, M_, 3*C_, C_);
    // RoPE q,k
    rope_k<<<dim3((B_*T_*C_/2)/256, 2), 256, 0, stream>>>(q_bf, k_bf);
    // attention
    attn_k<<<dim3(T_/64, B_*H_), 256, 0, stream>>>(q_bf, k_bf, vt_bf, y_bf);
    // output proj + residual
    transpose_bf<<<dim3(32, 32), 256, 0, stream>>>(Wo + wOff, wt_bf, C_, C_);
    gemm_bt<1><<<dim3(8, 16), 256, 0, stream>>>(y_bf, wt_bf,
        bo + l*C_, nullptr, nullptr, h, h, nullptr, nullptr, M_, C_, C_);
    // LN2
    ln_k<0><<<M_, 256, 0, stream>>>(h, ln2s + l*C_, ln2b + l*C_, a_bf);
    // FFN1 + GELU
    transpose_bf<<<dim3(128, 32), 256, 0, stream>>>(W1 + fOff, wt_bf, C_, DFF_);
    gemm_bt<2><<<dim3(32, 16), 256, 0, stream>>>(a_bf, wt_bf,
        b1 + l*DFF_, nullptr, nullptr, nullptr, mid_bf, nullptr, nullptr, M_, DFF_, C_);
    // FFN2 + residual
    transpose_bf<<<dim3(32, 128), 256, 0, stream>>>(W2 + fOff, wt_bf, DFF_, C_);
    gemm_bt<1><<<dim3(8, 16), 256, 0, stream>>>(mid_bf, wt_bf,
        b2 + l*C_, nullptr, nullptr, h, h, nullptr, nullptr, M_, C_, DFF_);
  }
  // final LN -> f32 out
  ln_k<1><<<M_, 256, 0, stream>>>(h, lnfs, lnfb, d_out);
}

// Round 4
// 1982.922 us; speedup vs baseline: 1.2696x; 1.2696x over previous
//
#include <hip/hip_runtime.h>
#include <cstdint>
#include <cstddef>

// Problem constants
#define L_   8
#define B_   2
#define T_   1024
#define C_   1024
#define H_   16
#define DH_  64
#define DFF_ 4096
#define M_   2048  // B_*T_

typedef __attribute__((ext_vector_type(4))) float f32x4;
typedef __attribute__((ext_vector_type(8))) short short8_t;
typedef __attribute__((ext_vector_type(8))) __bf16 bf16x8_t;
typedef __attribute__((ext_vector_type(4))) unsigned short ushort4_t;

__device__ __forceinline__ float bf2f(unsigned short u) {
  unsigned int i = ((unsigned int)u) << 16;
  return __builtin_bit_cast(float, i);
}
__device__ __forceinline__ unsigned short f2bf(float f) {
  unsigned int u = __builtin_bit_cast(unsigned int, f);
  u += 0x7fff + ((u >> 16) & 1);   // RNE
  return (unsigned short)(u >> 16);
}
__device__ __forceinline__ f32x4 mfma16x16x32(short8_t a, short8_t b, f32x4 c) {
  return __builtin_amdgcn_mfma_f32_16x16x32_bf16(
      __builtin_bit_cast(bf16x8_t, a), __builtin_bit_cast(bf16x8_t, b), c, 0, 0, 0);
}
__device__ __forceinline__ void async_copy16(const void* g, void* l) {
  __builtin_amdgcn_global_load_lds(
      (const __attribute__((address_space(1))) unsigned int*)g,
      (__attribute__((address_space(3))) unsigned int*)l, 16, 0, 0);
}

// ---------------------------------------------------------------------------
// LayerNorm: one block per row (C=1024, 256 threads -> 1 float4/thread)
// ---------------------------------------------------------------------------
template<int OUTF32>
__global__ __launch_bounds__(256) void ln_k(const float* __restrict__ X,
                                            const float* __restrict__ gam,
                                            const float* __restrict__ bet,
                                            void* __restrict__ out) {
  const int row = blockIdx.x;
  const int tid = threadIdx.x;
  const int lane = tid & 63, w = tid >> 6;
  const float4 v = ((const float4*)(X + (size_t)row * C_))[tid];
  float sum = v.x + v.y + v.z + v.w;
  float sq  = v.x*v.x + v.y*v.y + v.z*v.z + v.w*v.w;
#pragma unroll
  for (int d = 1; d < 64; d <<= 1) {
    sum += __shfl_xor(sum, d, 64);
    sq  += __shfl_xor(sq,  d, 64);
  }
  __shared__ float red[8];
  if (lane == 0) { red[w] = sum; red[4 + w] = sq; }
  __syncthreads();
  sum = red[0] + red[1] + red[2] + red[3];
  sq  = red[4] + red[5] + red[6] + red[7];
  const float mean = sum * (1.0f / C_);
  const float var  = sq * (1.0f / C_) - mean * mean;
  const float inv  = rsqrtf(var + 1e-5f);
  const int col = tid * 4;
  const float xs[4] = { v.x, v.y, v.z, v.w };
  if (OUTF32) {
    float4 ov;
    ov.x = (xs[0]-mean)*inv*gam[col+0] + bet[col+0];
    ov.y = (xs[1]-mean)*inv*gam[col+1] + bet[col+1];
    ov.z = (xs[2]-mean)*inv*gam[col+2] + bet[col+2];
    ov.w = (xs[3]-mean)*inv*gam[col+3] + bet[col+3];
    ((float4*)((float*)out + (size_t)row * C_))[tid] = ov;
  } else {
    ushort4_t ov;
#pragma unroll
    for (int i = 0; i < 4; ++i)
      ov[i] = f2bf((xs[i]-mean)*inv*gam[col+i] + bet[col+i]);
    *(ushort4_t*)((unsigned short*)out + (size_t)row * C_ + col) = ov;
  }
}

// ---------------------------------------------------------------------------
// Transpose + f32->bf16: W (R x Cc) -> Wt (Cc x R), 32x32 LDS tiles
// ---------------------------------------------------------------------------
__global__ __launch_bounds__(256) void transpose_bf(const float* __restrict__ W,
                                                    unsigned short* __restrict__ Wt,
                                                    int R, int Cc) {
  __shared__ float tile[32][33];
  const int c0 = blockIdx.x * 32, r0 = blockIdx.y * 32;
  const int tx = threadIdx.x & 31, ty = threadIdx.x >> 5;  // ty in 0..7
#pragma unroll
  for (int i = 0; i < 4; ++i)
    tile[ty + 8*i][tx] = W[(size_t)(r0 + ty + 8*i) * Cc + c0 + tx];
  __syncthreads();
#pragma unroll
  for (int i = 0; i < 4; ++i)
    Wt[(size_t)(c0 + ty + 8*i) * R + r0 + tx] = f2bf(tile[tx][ty + 8*i]);
}

// ---------------------------------------------------------------------------
// GEMM: C[M,N] = A[M,K] (bf16 row-major) . Bt[N,K] (bf16 row-major = W^T)
// 64x128 tile, BK=32, 4 waves (2x2) of 32x64. blockIdx.z = K-split slice.
// EPI 0: QKV (N=3072): +bias{q,k,v}; q,k -> bf16 (B,T,C); v -> bf16 (B,H,DH,T)
// EPI 2: +bias0, exact GELU, write bf16
// EPI 3: write f32 partial to out0[z][M][N]   (split-K path, no bias)
// ---------------------------------------------------------------------------
template<int EPI>
__global__ __launch_bounds__(256) void gemm64(
    const unsigned short* __restrict__ A,
    const unsigned short* __restrict__ Bt,
    const float* __restrict__ bias0,
    const float* __restrict__ bias1,
    const float* __restrict__ bias2,
    void* __restrict__ out0, void* __restrict__ out1, void* __restrict__ out2,
    int M, int N, int K) {
  __shared__ __align__(16) unsigned short As[64 * 32];
  __shared__ __align__(16) unsigned short Bs[128 * 32];
  const int tid = threadIdx.x;
  const int lane = tid & 63;
  const int w = tid >> 6;
  const int ln15 = lane & 15, lg = lane >> 4;
  const int row0 = blockIdx.y * 64, col0 = blockIdx.x * 128;
  const int wr = w >> 1, wc = w & 1;

  const int kper = K / gridDim.z;
  const int k0 = blockIdx.z * kper;

  f32x4 acc[2][4] = {};

  // staging: chunk c covers LDS bytes [c*16, c*16+16) of a (rows x 32) bf16 tile
  // chunk c -> element row (c>>2), col (c&3)*8
  const int rA  = tid >> 2,          ccA = (tid & 3) * 8;   // A: 256 chunks
  const int rB0 = tid >> 2,          ccB = (tid & 3) * 8;   // B: 512 chunks
  const int rB1 = (256 + tid) >> 2;                         // (256+tid)&3 == tid&3

  for (int kt = k0; kt < k0 + kper; kt += 32) {
    async_copy16(A  + (size_t)(row0 + rA)  * K + kt + ccA, (char*)As + ((size_t)w * 64) * 16);
    async_copy16(Bt + (size_t)(col0 + rB0) * K + kt + ccB, (char*)Bs + ((size_t)w * 64) * 16);
    async_copy16(Bt + (size_t)(col0 + rB1) * K + kt + ccB, (char*)Bs + ((size_t)(256 + w * 64)) * 16);
    __syncthreads();
    short8_t af[2], bfr[4];
#pragma unroll
    for (int m = 0; m < 2; ++m)
      af[m] = *(const short8_t*)(As + (wr*32 + m*16 + ln15) * 32 + lg * 8);
#pragma unroll
    for (int n = 0; n < 4; ++n)
      bfr[n] = *(const short8_t*)(Bs + (wc*64 + n*16 + ln15) * 32 + lg * 8);
#pragma unroll
    for (int m = 0; m < 2; ++m)
#pragma unroll
      for (int n = 0; n < 4; ++n)
        acc[m][n] = mfma16x16x32(af[m], bfr[n], acc[m][n]);
    __syncthreads();
  }

#pragma unroll
  for (int m = 0; m < 2; ++m) {
#pragma unroll
    for (int n = 0; n < 4; ++n) {
#pragma unroll
      for (int r = 0; r < 4; ++r) {
        const int rg = row0 + wr*32 + m*16 + lg*4 + r;
        const int cg = col0 + wc*64 + n*16 + ln15;
        float v = acc[m][n][r];
        if (EPI == 0) {
          if (cg < 1024) {
            v += bias0[cg];
            ((unsigned short*)out0)[(size_t)rg * C_ + cg] = f2bf(v);
          } else if (cg < 2048) {
            v += bias1[cg - 1024];
            ((unsigned short*)out1)[(size_t)rg * C_ + (cg - 1024)] = f2bf(v);
          } else {
            const int ch = cg - 2048;
            v += bias2[ch];
            const int hh = ch >> 6, dh = ch & 63;
            const int bb = rg >> 10, t = rg & 1023;
            // Vt layout: (B,H,DH,T)
            ((unsigned short*)out2)[(((size_t)(bb * H_ + hh) * DH_ + dh) << 10) + t] = f2bf(v);
          }
        } else if (EPI == 2) {
          v += bias0[cg];
          v = 0.5f * v * (1.0f + erff(v * 0.70710678118654752f));
          ((unsigned short*)out0)[(size_t)rg * N + cg] = f2bf(v);
        } else {
          ((float*)out0)[((size_t)blockIdx.z * M_ + rg) * (size_t)N + cg] = v;
        }
      }
    }
  }
}

// ---------------------------------------------------------------------------
// Split-K reduce + bias + residual (in-place on h): h += bias[col] + sum parts
// N fixed at C_ (1024). float4 per thread.
// ---------------------------------------------------------------------------
template<int NS>
__global__ __launch_bounds__(256) void reduce_k(float* __restrict__ h,
                                                const float* __restrict__ bias,
                                                const float* __restrict__ part) {
  const size_t idx = (size_t)blockIdx.x * 256 + threadIdx.x;  // float4 index
  const size_t i4 = idx * 4;
  const int colg = (int)(i4 & (C_ - 1)) >> 2;
  float4 acc = ((float4*)h)[idx];
  const float4 b = ((const float4*)bias)[colg];
  acc.x += b.x; acc.y += b.y; acc.z += b.z; acc.w += b.w;
#pragma unroll
  for (int z = 0; z < NS; ++z) {
    const float4 p = ((const float4*)(part + (size_t)z * M_ * C_))[idx];
    acc.x += p.x; acc.y += p.y; acc.z += p.z; acc.w += p.w;
  }
  ((float4*)h)[idx] = acc;
}

// ---------------------------------------------------------------------------
// RoPE in-place on bf16 q or k, (B,T,C) layout; pair = channels (2j, 2j+1)
// ---------------------------------------------------------------------------
__global__ __launch_bounds__(256) void rope_k(unsigned short* __restrict__ Q,
                                              unsigned short* __restrict__ Kb) {
  const size_t p = (size_t)blockIdx.x * 256 + threadIdx.x;  // pair index
  unsigned short* ptr = blockIdx.y ? Kb : Q;
  const int cpair = (int)(p & 511);          // C/2 = 512 pairs per row
  const int t = (int)((p >> 9) & 1023);
  const int j = cpair & 31;                  // DH/2 = 32 pairs per head
  const float ang = (float)t * expf((float)j * -0.28782313662425572f);
  float cs, sn;
  sincosf(ang, &sn, &cs);
  unsigned int u = *(unsigned int*)(ptr + 2 * p);
  const float x0 = bf2f((unsigned short)(u & 0xffff));
  const float x1 = bf2f((unsigned short)(u >> 16));
  const float o0 = x0 * cs - x1 * sn;
  const float o1 = x0 * sn + x1 * cs;
  *(unsigned int*)(ptr + 2 * p) = (unsigned int)f2bf(o0) | ((unsigned int)f2bf(o1) << 16);
}

// ---------------------------------------------------------------------------
// Flash attention: grid (T/64, B*H), 256 threads (4 waves, 16 q-rows each).
// Q,K bf16 (B,T,C); Vt bf16 (B,H,DH,T); Y bf16 (B,T,C). Causal, scale 1/8.
// ---------------------------------------------------------------------------
__global__ __launch_bounds__(256) void attn_k(const unsigned short* __restrict__ Q,
                                              const unsigned short* __restrict__ Kb,
                                              const unsigned short* __restrict__ Vt,
                                              unsigned short* __restrict__ Y) {
  __shared__ __align__(16) unsigned short P[64 * 64];
  const int tid = threadIdx.x, lane = tid & 63, w = tid >> 6;
  const int ln15 = lane & 15, lg = lane >> 4;
  const int qb = blockIdx.x;
  const int bh = blockIdx.y;
  const int b = bh >> 4, h = bh & 15;
  const int q0 = qb * 64;

  short8_t aq[2];
  const int qrow = q0 + w * 16 + ln15;
#pragma unroll
  for (int c = 0; c < 2; ++c)
    aq[c] = *(const short8_t*)(Q + ((size_t)(b * T_ + qrow)) * C_ + h * DH_ + c * 32 + lg * 8);

  float m_run[4], l_run[4];
  f32x4 o[4] = {};
#pragma unroll
  for (int r = 0; r < 4; ++r) { m_run[r] = -1e30f; l_run[r] = 0.0f; }

  const int rowg0 = q0 + w * 16 + lg * 4;

  for (int kb = 0; kb <= qb; ++kb) {
    f32x4 s[4] = {};
#pragma unroll
    for (int n = 0; n < 4; ++n) {
#pragma unroll
      for (int c = 0; c < 2; ++c) {
        const short8_t bk = *(const short8_t*)(Kb +
            ((size_t)(b * T_ + kb * 64 + n * 16 + ln15)) * C_ + h * DH_ + c * 32 + lg * 8);
        s[n] = mfma16x16x32(aq[c], bk, s[n]);
      }
    }
    const bool diag = (kb == qb);
    float mx[4];
#pragma unroll
    for (int r = 0; r < 4; ++r) {
      float mr = -1e30f;
#pragma unroll
      for (int n = 0; n < 4; ++n) {
        float v = s[n][r] * 0.125f;
        if (diag && (kb * 64 + n * 16 + ln15) > (rowg0 + r)) v = -1e30f;
        s[n][r] = v;
        mr = fmaxf(mr, v);
      }
      mx[r] = mr;
    }
#pragma unroll
    for (int d = 1; d < 16; d <<= 1)
#pragma unroll
      for (int r = 0; r < 4; ++r) mx[r] = fmaxf(mx[r], __shfl_xor(mx[r], d, 64));

#pragma unroll
    for (int r = 0; r < 4; ++r) {
      const float mn = fmaxf(m_run[r], mx[r]);
      const float sc = expf(m_run[r] - mn);
      m_run[r] = mn;
      float rs = 0.0f;
#pragma unroll
      for (int n = 0; n < 4; ++n) {
        const float pv = expf(s[n][r] - mn);
        s[n][r] = pv;
        rs += pv;
      }
#pragma unroll
      for (int d = 1; d < 16; d <<= 1) rs += __shfl_xor(rs, d, 64);
      l_run[r] = l_run[r] * sc + rs;
#pragma unroll
      for (int n = 0; n < 4; ++n) o[n][r] *= sc;
    }
#pragma unroll
    for (int r = 0; r < 4; ++r)
#pragma unroll
      for (int n = 0; n < 4; ++n)
        P[(w * 16 + lg * 4 + r) * 64 + n * 16 + ln15] = f2bf(s[n][r]);
    __syncthreads();
#pragma unroll
    for (int c = 0; c < 2; ++c) {
      const short8_t pa = *(const short8_t*)(P + (w * 16 + ln15) * 64 + c * 32 + lg * 8);
#pragma unroll
      for (int n = 0; n < 4; ++n) {
        const short8_t vb = *(const short8_t*)(Vt +
            ((size_t)(bh * DH_ + n * 16 + ln15)) * T_ + kb * 64 + c * 32 + lg * 8);
        o[n] = mfma16x16x32(pa, vb, o[n]);
      }
    }
    __syncthreads();
  }
#pragma unroll
  for (int n = 0; n < 4; ++n)
#pragma unroll
    for (int r = 0; r < 4; ++r) {
      const float val = o[n][r] / l_run[r];
      const int rg = rowg0 + r;
      Y[((size_t)(b * T_ + rg)) * C_ + h * DH_ + n * 16 + ln15] = f2bf(val);
    }
}

// ---------------------------------------------------------------------------
extern "C" void kernel_launch(void* const* d_in, const int* in_sizes, int n_in,
                              void* d_out, int out_size, void* d_ws, size_t ws_size,
                              hipStream_t stream) {
  const float* x    = (const float*)d_in[0];
  const float* Wq   = (const float*)d_in[1];
  const float* bq   = (const float*)d_in[2];
  const float* Wk   = (const float*)d_in[3];
  const float* bk   = (const float*)d_in[4];
  const float* Wv   = (const float*)d_in[5];
  const float* bv   = (const float*)d_in[6];
  const float* Wo   = (const float*)d_in[7];
  const float* bo   = (const float*)d_in[8];
  const float* ln1s = (const float*)d_in[9];
  const float* ln1b = (const float*)d_in[10];
  const float* ln2s = (const float*)d_in[11];
  const float* ln2b = (const float*)d_in[12];
  const float* W1   = (const float*)d_in[13];
  const float* b1   = (const float*)d_in[14];
  const float* W2   = (const float*)d_in[15];
  const float* b2   = (const float*)d_in[16];
  const float* lnfs = (const float*)d_in[17];
  const float* lnfb = (const float*)d_in[18];

  const size_t MB = (size_t)1 << 20;
  char* ws = (char*)d_ws;
  float*          h      = (float*)(ws + 0);              //  8 MB (B,T,C) f32
  unsigned short* a_bf   = (unsigned short*)(ws + 8*MB);  //  4 MB
  unsigned short* q_bf   = (unsigned short*)(ws + 12*MB); //  4 MB
  unsigned short* k_bf   = (unsigned short*)(ws + 16*MB); //  4 MB
  unsigned short* vt_bf  = (unsigned short*)(ws + 20*MB); //  4 MB (B,H,DH,T)
  unsigned short* y_bf   = (unsigned short*)(ws + 24*MB); //  4 MB
  unsigned short* mid_bf = (unsigned short*)(ws + 28*MB); // 16 MB (M,DFF)
  unsigned short* wt_bf  = (unsigned short*)(ws + 44*MB); //  8 MB
  float*          part   = (float*)(ws + 52*MB);          // 32 MB (<=4 splits x 8 MB)

  hipMemcpyAsync(h, x, (size_t)M_ * C_ * sizeof(float), hipMemcpyDeviceToDevice, stream);

  for (int l = 0; l < L_; ++l) {
    const size_t wOff = (size_t)l * C_ * C_;
    const size_t fOff = (size_t)l * C_ * DFF_;
    // LN1 -> a_bf
    ln_k<0><<<M_, 256, 0, stream>>>(h, ln1s + l*C_, ln1b + l*C_, a_bf);
    // W^T for q,k,v (concatenated 3072 x 1024)
    transpose_bf<<<dim3(32, 32), 256, 0, stream>>>(Wq + wOff, wt_bf,           C_, C_);
    transpose_bf<<<dim3(32, 32), 256, 0, stream>>>(Wk + wOff, wt_bf + C_*C_,   C_, C_);
    transpose_bf<<<dim3(32, 32), 256, 0, stream>>>(Wv + wOff, wt_bf + 2*C_*C_, C_, C_);
    // fused QKV GEMM: 768 blocks
    gemm64<0><<<dim3(24, 32, 1), 256, 0, stream>>>(a_bf, wt_bf,
        bq + l*C_, bk + l*C_, bv + l*C_, q_bf, k_bf, vt_bf, M_, 3*C_, C_);
    // RoPE q,k
    rope_k<<<dim3((B_*T_*C_/2)/256, 2), 256, 0, stream>>>(q_bf, k_bf);
    // attention
    attn_k<<<dim3(T_/64, B_*H_), 256, 0, stream>>>(q_bf, k_bf, vt_bf, y_bf);
    // output proj, split-K=2 -> partials, then reduce(+bo, +resid in place)
    transpose_bf<<<dim3(32, 32), 256, 0, stream>>>(Wo + wOff, wt_bf, C_, C_);
    gemm64<3><<<dim3(8, 32, 2), 256, 0, stream>>>(y_bf, wt_bf,
        nullptr, nullptr, nullptr, part, nullptr, nullptr, M_, C_, C_);
    reduce_k<2><<<(M_*C_/4)/256, 256, 0, stream>>>(h, bo + l*C_, part);
    // LN2
    ln_k<0><<<M_, 256, 0, stream>>>(h, ln2s + l*C_, ln2b + l*C_, a_bf);
    // FFN1 + GELU: 1024 blocks
    transpose_bf<<<dim3(128, 32), 256, 0, stream>>>(W1 + fOff, wt_bf, C_, DFF_);
    gemm64<2><<<dim3(32, 32, 1), 256, 0, stream>>>(a_bf, wt_bf,
        b1 + l*DFF_, nullptr, nullptr, mid_bf, nullptr, nullptr, M_, DFF_, C_);
    // FFN2, split-K=4 -> partials, then reduce(+b2, +resid in place)
    transpose_bf<<<dim3(32, 128), 256, 0, stream>>>(W2 + fOff, wt_bf, DFF_, C_);
    gemm64<3><<<dim3(8, 32, 4), 256, 0, stream>>>(mid_bf, wt_bf,
        nullptr, nullptr, nullptr, part, nullptr, nullptr, M_, C_, DFF_);
    reduce_k<4><<<(M_*C_/4)/256, 256, 0, stream>>>(h, b2 + l*C_, part);
  }
  // final LN -> f32 out
  ln_k<1><<<M_, 256, 0, stream>>>(h, lnfs, lnfb, d_out);
}

// Round 5
// 1845.850 us; speedup vs baseline: 1.3639x; 1.0743x over previous
//
#include <hip/hip_runtime.h>
#include <cstdint>
#include <cstddef>

// Problem constants
#define L_   8
#define B_   2
#define T_   1024
#define C_   1024
#define H_   16
#define DH_  64
#define DFF_ 4096
#define M_   2048  // B_*T_

typedef __attribute__((ext_vector_type(4))) float f32x4;
typedef __attribute__((ext_vector_type(8))) short short8_t;
typedef __attribute__((ext_vector_type(8))) __bf16 bf16x8_t;
typedef __attribute__((ext_vector_type(4))) unsigned short ushort4_t;

__device__ __forceinline__ float bf2f(unsigned short u) {
  unsigned int i = ((unsigned int)u) << 16;
  return __builtin_bit_cast(float, i);
}
__device__ __forceinline__ unsigned short f2bf(float f) {
  unsigned int u = __builtin_bit_cast(unsigned int, f);
  u += 0x7fff + ((u >> 16) & 1);   // RNE
  return (unsigned short)(u >> 16);
}
__device__ __forceinline__ f32x4 mfma16x16x32(short8_t a, short8_t b, f32x4 c) {
  return __builtin_amdgcn_mfma_f32_16x16x32_bf16(
      __builtin_bit_cast(bf16x8_t, a), __builtin_bit_cast(bf16x8_t, b), c, 0, 0, 0);
}
__device__ __forceinline__ void async_copy16(const void* g, void* l) {
  __builtin_amdgcn_global_load_lds(
      (const __attribute__((address_space(1))) unsigned int*)g,
      (__attribute__((address_space(3))) unsigned int*)l, 16, 0, 0);
}

// ---------------------------------------------------------------------------
// LayerNorm: one block per row (C=1024, 256 threads -> 1 float4/thread)
// ---------------------------------------------------------------------------
template<int OUTF32>
__global__ __launch_bounds__(256) void ln_k(const float* __restrict__ X,
                                            const float* __restrict__ gam,
                                            const float* __restrict__ bet,
                                            void* __restrict__ out) {
  const int row = blockIdx.x;
  const int tid = threadIdx.x;
  const int lane = tid & 63, w = tid >> 6;
  const float4 v = ((const float4*)(X + (size_t)row * C_))[tid];
  float sum = v.x + v.y + v.z + v.w;
  float sq  = v.x*v.x + v.y*v.y + v.z*v.z + v.w*v.w;
#pragma unroll
  for (int d = 1; d < 64; d <<= 1) {
    sum += __shfl_xor(sum, d, 64);
    sq  += __shfl_xor(sq,  d, 64);
  }
  __shared__ float red[8];
  if (lane == 0) { red[w] = sum; red[4 + w] = sq; }
  __syncthreads();
  sum = red[0] + red[1] + red[2] + red[3];
  sq  = red[4] + red[5] + red[6] + red[7];
  const float mean = sum * (1.0f / C_);
  const float var  = sq * (1.0f / C_) - mean * mean;
  const float inv  = rsqrtf(var + 1e-5f);
  const int col = tid * 4;
  const float xs[4] = { v.x, v.y, v.z, v.w };
  if (OUTF32) {
    float4 ov;
    ov.x = (xs[0]-mean)*inv*gam[col+0] + bet[col+0];
    ov.y = (xs[1]-mean)*inv*gam[col+1] + bet[col+1];
    ov.z = (xs[2]-mean)*inv*gam[col+2] + bet[col+2];
    ov.w = (xs[3]-mean)*inv*gam[col+3] + bet[col+3];
    ((float4*)((float*)out + (size_t)row * C_))[tid] = ov;
  } else {
    ushort4_t ov;
#pragma unroll
    for (int i = 0; i < 4; ++i)
      ov[i] = f2bf((xs[i]-mean)*inv*gam[col+i] + bet[col+i]);
    *(ushort4_t*)((unsigned short*)out + (size_t)row * C_ + col) = ov;
  }
}

// ---------------------------------------------------------------------------
// Transpose + f32->bf16: W (R x Cc) -> Wt (Cc x R), 32x32 LDS tiles
// ---------------------------------------------------------------------------
__global__ __launch_bounds__(256) void transpose_bf(const float* __restrict__ W,
                                                    unsigned short* __restrict__ Wt,
                                                    int R, int Cc) {
  __shared__ float tile[32][33];
  const int c0 = blockIdx.x * 32, r0 = blockIdx.y * 32;
  const int tx = threadIdx.x & 31, ty = threadIdx.x >> 5;  // ty in 0..7
#pragma unroll
  for (int i = 0; i < 4; ++i)
    tile[ty + 8*i][tx] = W[(size_t)(r0 + ty + 8*i) * Cc + c0 + tx];
  __syncthreads();
#pragma unroll
  for (int i = 0; i < 4; ++i)
    Wt[(size_t)(c0 + ty + 8*i) * R + r0 + tx] = f2bf(tile[tx][ty + 8*i]);
}

// ---------------------------------------------------------------------------
// GEMM: C[M,N] = A[M,K] (bf16 row-major) . Bt[N,K] (bf16 row-major = W^T)
// 64x128 tile, BK=32, 4 waves (2x2) of 32x64. blockIdx.z = K-split slice.
// EPI 0: QKV (N=3072): +bias{q,k,v}; q,k -> bf16 (B,T,C); v -> bf16 (B,H,DH,T)
// EPI 2: +bias0, exact GELU, write bf16
// EPI 3: write f32 partial to out0[z][M][N]   (split-K path, no bias)
// ---------------------------------------------------------------------------
template<int EPI>
__global__ __launch_bounds__(256) void gemm64(
    const unsigned short* __restrict__ A,
    const unsigned short* __restrict__ Bt,
    const float* __restrict__ bias0,
    const float* __restrict__ bias1,
    const float* __restrict__ bias2,
    void* __restrict__ out0, void* __restrict__ out1, void* __restrict__ out2,
    int M, int N, int K) {
  __shared__ __align__(16) unsigned short As[64 * 32];
  __shared__ __align__(16) unsigned short Bs[128 * 32];
  const int tid = threadIdx.x;
  const int lane = tid & 63;
  const int w = tid >> 6;
  const int ln15 = lane & 15, lg = lane >> 4;
  const int row0 = blockIdx.y * 64, col0 = blockIdx.x * 128;
  const int wr = w >> 1, wc = w & 1;

  const int kper = K / gridDim.z;
  const int k0 = blockIdx.z * kper;

  f32x4 acc[2][4] = {};

  const int rA  = tid >> 2,          ccA = (tid & 3) * 8;   // A: 256 chunks
  const int rB0 = tid >> 2,          ccB = (tid & 3) * 8;   // B: 512 chunks
  const int rB1 = (256 + tid) >> 2;                         // (256+tid)&3 == tid&3

  for (int kt = k0; kt < k0 + kper; kt += 32) {
    async_copy16(A  + (size_t)(row0 + rA)  * K + kt + ccA, (char*)As + ((size_t)w * 64) * 16);
    async_copy16(Bt + (size_t)(col0 + rB0) * K + kt + ccB, (char*)Bs + ((size_t)w * 64) * 16);
    async_copy16(Bt + (size_t)(col0 + rB1) * K + kt + ccB, (char*)Bs + ((size_t)(256 + w * 64)) * 16);
    __syncthreads();
    short8_t af[2], bfr[4];
#pragma unroll
    for (int m = 0; m < 2; ++m)
      af[m] = *(const short8_t*)(As + (wr*32 + m*16 + ln15) * 32 + lg * 8);
#pragma unroll
    for (int n = 0; n < 4; ++n)
      bfr[n] = *(const short8_t*)(Bs + (wc*64 + n*16 + ln15) * 32 + lg * 8);
#pragma unroll
    for (int m = 0; m < 2; ++m)
#pragma unroll
      for (int n = 0; n < 4; ++n)
        acc[m][n] = mfma16x16x32(af[m], bfr[n], acc[m][n]);
    __syncthreads();
  }

#pragma unroll
  for (int m = 0; m < 2; ++m) {
#pragma unroll
    for (int n = 0; n < 4; ++n) {
#pragma unroll
      for (int r = 0; r < 4; ++r) {
        const int rg = row0 + wr*32 + m*16 + lg*4 + r;
        const int cg = col0 + wc*64 + n*16 + ln15;
        float v = acc[m][n][r];
        if (EPI == 0) {
          if (cg < 1024) {
            v += bias0[cg];
            ((unsigned short*)out0)[(size_t)rg * C_ + cg] = f2bf(v);
          } else if (cg < 2048) {
            v += bias1[cg - 1024];
            ((unsigned short*)out1)[(size_t)rg * C_ + (cg - 1024)] = f2bf(v);
          } else {
            const int ch = cg - 2048;
            v += bias2[ch];
            const int hh = ch >> 6, dh = ch & 63;
            const int bb = rg >> 10, t = rg & 1023;
            // Vt layout: (B,H,DH,T)
            ((unsigned short*)out2)[(((size_t)(bb * H_ + hh) * DH_ + dh) << 10) + t] = f2bf(v);
          }
        } else if (EPI == 2) {
          v += bias0[cg];
          v = 0.5f * v * (1.0f + erff(v * 0.70710678118654752f));
          ((unsigned short*)out0)[(size_t)rg * N + cg] = f2bf(v);
        } else {
          ((float*)out0)[((size_t)blockIdx.z * M_ + rg) * (size_t)N + cg] = v;
        }
      }
    }
  }
}

// ---------------------------------------------------------------------------
// Split-K reduce + bias + residual (in-place on h): h += bias[col] + sum parts
// ---------------------------------------------------------------------------
template<int NS>
__global__ __launch_bounds__(256) void reduce_k(float* __restrict__ h,
                                                const float* __restrict__ bias,
                                                const float* __restrict__ part) {
  const size_t idx = (size_t)blockIdx.x * 256 + threadIdx.x;  // float4 index
  const size_t i4 = idx * 4;
  const int colg = (int)(i4 & (C_ - 1)) >> 2;
  float4 acc = ((float4*)h)[idx];
  const float4 b = ((const float4*)bias)[colg];
  acc.x += b.x; acc.y += b.y; acc.z += b.z; acc.w += b.w;
#pragma unroll
  for (int z = 0; z < NS; ++z) {
    const float4 p = ((const float4*)(part + (size_t)z * M_ * C_))[idx];
    acc.x += p.x; acc.y += p.y; acc.z += p.z; acc.w += p.w;
  }
  ((float4*)h)[idx] = acc;
}

// ---------------------------------------------------------------------------
// RoPE in-place on bf16 q or k, (B,T,C) layout; pair = channels (2j, 2j+1)
// ---------------------------------------------------------------------------
__global__ __launch_bounds__(256) void rope_k(unsigned short* __restrict__ Q,
                                              unsigned short* __restrict__ Kb) {
  const size_t p = (size_t)blockIdx.x * 256 + threadIdx.x;  // pair index
  unsigned short* ptr = blockIdx.y ? Kb : Q;
  const int cpair = (int)(p & 511);          // C/2 = 512 pairs per row
  const int t = (int)((p >> 9) & 1023);
  const int j = cpair & 31;                  // DH/2 = 32 pairs per head
  const float ang = (float)t * expf((float)j * -0.28782313662425572f);
  float cs, sn;
  sincosf(ang, &sn, &cs);
  unsigned int u = *(unsigned int*)(ptr + 2 * p);
  const float x0 = bf2f((unsigned short)(u & 0xffff));
  const float x1 = bf2f((unsigned short)(u >> 16));
  const float o0 = x0 * cs - x1 * sn;
  const float o1 = x0 * sn + x1 * cs;
  *(unsigned int*)(ptr + 2 * p) = (unsigned int)f2bf(o0) | ((unsigned int)f2bf(o1) << 16);
}

// ---------------------------------------------------------------------------
// Flash attention, wave-independent: grid (T/16, B*H), 64 threads (1 wave).
// Each wave owns 16 q-rows; KV tiles of 64. Q,K bf16 (B,T,C); Vt (B,H,DH,T).
// Softmax in exp2 domain; mask only in the final (diagonal) tile.
// ---------------------------------------------------------------------------
template<bool MASK>
__device__ __forceinline__ void attn_tile(
    const int kb, const int ln15, const int lg, const int rowg0,
    const unsigned short* __restrict__ Kp,   // Kb + (b*T_+ln15)*C_ + h*DH_ + lg*8
    const unsigned short* __restrict__ Vp,   // Vt + (bh*DH_+ln15)*T_ + lg*8
    const short8_t aq0, const short8_t aq1,
    float* __restrict__ m_run, float* __restrict__ l_run,
    f32x4* __restrict__ o, unsigned short* __restrict__ P) {
  const unsigned short* kt = Kp + (size_t)kb * 64 * C_;
  const unsigned short* vt = Vp + kb * 64;
  short8_t bk[4][2], vb[2][4];
#pragma unroll
  for (int n = 0; n < 4; ++n) {
    bk[n][0] = *(const short8_t*)(kt + (size_t)n * 16 * C_);
    bk[n][1] = *(const short8_t*)(kt + (size_t)n * 16 * C_ + 32);
  }
  f32x4 s[4] = {};
#pragma unroll
  for (int n = 0; n < 4; ++n) {
    s[n] = mfma16x16x32(aq0, bk[n][0], s[n]);
    s[n] = mfma16x16x32(aq1, bk[n][1], s[n]);
  }
  // issue V loads now so they overlap the softmax VALU phase
#pragma unroll
  for (int c = 0; c < 2; ++c)
#pragma unroll
    for (int n = 0; n < 4; ++n)
      vb[c][n] = *(const short8_t*)(vt + (size_t)n * 16 * T_ + c * 32);

  const float SCL = 0.18033688011116012f;   // (1/8) * log2(e)
  float mx[4];
#pragma unroll
  for (int r = 0; r < 4; ++r) {
    float mr = -1e30f;
#pragma unroll
    for (int n = 0; n < 4; ++n) {
      float v = s[n][r] * SCL;
      if (MASK && (kb * 64 + n * 16 + ln15) > (rowg0 + r)) v = -1e30f;
      s[n][r] = v;
      mr = fmaxf(mr, v);
    }
    mx[r] = mr;
  }
#pragma unroll
  for (int d = 1; d < 16; d <<= 1)
#pragma unroll
    for (int r = 0; r < 4; ++r) mx[r] = fmaxf(mx[r], __shfl_xor(mx[r], d, 64));
#pragma unroll
  for (int r = 0; r < 4; ++r) {
    const float mn = fmaxf(m_run[r], mx[r]);
    const float scf = exp2f(m_run[r] - mn);
    m_run[r] = mn;
    float rs = 0.0f;
#pragma unroll
    for (int n = 0; n < 4; ++n) {
      const float pv = exp2f(s[n][r] - mn);
      s[n][r] = pv;
      rs += pv;
    }
#pragma unroll
    for (int d = 1; d < 16; d <<= 1) rs += __shfl_xor(rs, d, 64);
    l_run[r] = l_run[r] * scf + rs;
#pragma unroll
    for (int n = 0; n < 4; ++n) o[n][r] *= scf;
  }
  __syncthreads();   // single-wave: WAR fence (prior PV reads complete)
#pragma unroll
  for (int r = 0; r < 4; ++r)
#pragma unroll
    for (int n = 0; n < 4; ++n)
      P[(lg * 4 + r) * 64 + n * 16 + ln15] = f2bf(s[n][r]);
  __syncthreads();   // single-wave: RAW fence
#pragma unroll
  for (int c = 0; c < 2; ++c) {
    const short8_t pa = *(const short8_t*)(P + ln15 * 64 + c * 32 + lg * 8);
#pragma unroll
    for (int n = 0; n < 4; ++n)
      o[n] = mfma16x16x32(pa, vb[c][n], o[n]);
  }
}

__global__ __launch_bounds__(64) void attn_k(const unsigned short* __restrict__ Q,
                                             const unsigned short* __restrict__ Kb,
                                             const unsigned short* __restrict__ Vt,
                                             unsigned short* __restrict__ Y) {
  __shared__ __align__(16) unsigned short P[16 * 64];
  const int lane = threadIdx.x;
  const int ln15 = lane & 15, lg = lane >> 4;
  const int qt = blockIdx.x, bh = blockIdx.y;
  const int b = bh >> 4, h = bh & 15;
  const int q0 = qt * 16;

  short8_t aq0, aq1;
  {
    const unsigned short* qp = Q + ((size_t)(b * T_ + q0 + ln15)) * C_ + h * DH_ + lg * 8;
    aq0 = *(const short8_t*)(qp);
    aq1 = *(const short8_t*)(qp + 32);
  }
  float m_run[4] = { -1e30f, -1e30f, -1e30f, -1e30f };
  float l_run[4] = {};
  f32x4 o[4] = {};
  const int rowg0 = q0 + lg * 4;
  const unsigned short* Kp = Kb + ((size_t)b * T_ + ln15) * C_ + h * DH_ + lg * 8;
  const unsigned short* Vp = Vt + ((size_t)bh * DH_ + ln15) * T_ + lg * 8;

  const int kb_last = qt >> 2;
  for (int kb = 0; kb < kb_last; ++kb)
    attn_tile<false>(kb, ln15, lg, rowg0, Kp, Vp, aq0, aq1, m_run, l_run, o, P);
  attn_tile<true>(kb_last, ln15, lg, rowg0, Kp, Vp, aq0, aq1, m_run, l_run, o, P);

#pragma unroll
  for (int n = 0; n < 4; ++n)
#pragma unroll
    for (int r = 0; r < 4; ++r) {
      const float val = o[n][r] / l_run[r];
      Y[((size_t)(b * T_ + rowg0 + r)) * C_ + h * DH_ + n * 16 + ln15] = f2bf(val);
    }
}

// ---------------------------------------------------------------------------
extern "C" void kernel_launch(void* const* d_in, const int* in_sizes, int n_in,
                              void* d_out, int out_size, void* d_ws, size_t ws_size,
                              hipStream_t stream) {
  const float* x    = (const float*)d_in[0];
  const float* Wq   = (const float*)d_in[1];
  const float* bq   = (const float*)d_in[2];
  const float* Wk   = (const float*)d_in[3];
  const float* bk   = (const float*)d_in[4];
  const float* Wv   = (const float*)d_in[5];
  const float* bv   = (const float*)d_in[6];
  const float* Wo   = (const float*)d_in[7];
  const float* bo   = (const float*)d_in[8];
  const float* ln1s = (const float*)d_in[9];
  const float* ln1b = (const float*)d_in[10];
  const float* ln2s = (const float*)d_in[11];
  const float* ln2b = (const float*)d_in[12];
  const float* W1   = (const float*)d_in[13];
  const float* b1   = (const float*)d_in[14];
  const float* W2   = (const float*)d_in[15];
  const float* b2   = (const float*)d_in[16];
  const float* lnfs = (const float*)d_in[17];
  const float* lnfb = (const float*)d_in[18];

  const size_t MB = (size_t)1 << 20;
  char* ws = (char*)d_ws;
  float*          h      = (float*)(ws + 0);              //  8 MB (B,T,C) f32
  unsigned short* a_bf   = (unsigned short*)(ws + 8*MB);  //  4 MB
  unsigned short* q_bf   = (unsigned short*)(ws + 12*MB); //  4 MB
  unsigned short* k_bf   = (unsigned short*)(ws + 16*MB); //  4 MB
  unsigned short* vt_bf  = (unsigned short*)(ws + 20*MB); //  4 MB (B,H,DH,T)
  unsigned short* y_bf   = (unsigned short*)(ws + 24*MB); //  4 MB
  unsigned short* mid_bf = (unsigned short*)(ws + 28*MB); // 16 MB (M,DFF)
  unsigned short* wt_bf  = (unsigned short*)(ws + 44*MB); //  8 MB
  float*          part   = (float*)(ws + 52*MB);          // 32 MB (<=4 splits x 8 MB)

  hipMemcpyAsync(h, x, (size_t)M_ * C_ * sizeof(float), hipMemcpyDeviceToDevice, stream);

  for (int l = 0; l < L_; ++l) {
    const size_t wOff = (size_t)l * C_ * C_;
    const size_t fOff = (size_t)l * C_ * DFF_;
    // LN1 -> a_bf
    ln_k<0><<<M_, 256, 0, stream>>>(h, ln1s + l*C_, ln1b + l*C_, a_bf);
    // W^T for q,k,v (concatenated 3072 x 1024)
    transpose_bf<<<dim3(32, 32), 256, 0, stream>>>(Wq + wOff, wt_bf,           C_, C_);
    transpose_bf<<<dim3(32, 32), 256, 0, stream>>>(Wk + wOff, wt_bf + C_*C_,   C_, C_);
    transpose_bf<<<dim3(32, 32), 256, 0, stream>>>(Wv + wOff, wt_bf + 2*C_*C_, C_, C_);
    // fused QKV GEMM: 768 blocks
    gemm64<0><<<dim3(24, 32, 1), 256, 0, stream>>>(a_bf, wt_bf,
        bq + l*C_, bk + l*C_, bv + l*C_, q_bf, k_bf, vt_bf, M_, 3*C_, C_);
    // RoPE q,k
    rope_k<<<dim3((B_*T_*C_/2)/256, 2), 256, 0, stream>>>(q_bf, k_bf);
    // attention: 2048 wave-independent blocks
    attn_k<<<dim3(T_/16, B_*H_), 64, 0, stream>>>(q_bf, k_bf, vt_bf, y_bf);
    // output proj, split-K=2 -> partials, then reduce(+bo, +resid in place)
    transpose_bf<<<dim3(32, 32), 256, 0, stream>>>(Wo + wOff, wt_bf, C_, C_);
    gemm64<3><<<dim3(8, 32, 2), 256, 0, stream>>>(y_bf, wt_bf,
        nullptr, nullptr, nullptr, part, nullptr, nullptr, M_, C_, C_);
    reduce_k<2><<<(M_*C_/4)/256, 256, 0, stream>>>(h, bo + l*C_, part);
    // LN2
    ln_k<0><<<M_, 256, 0, stream>>>(h, ln2s + l*C_, ln2b + l*C_, a_bf);
    // FFN1 + GELU: 1024 blocks
    transpose_bf<<<dim3(128, 32), 256, 0, stream>>>(W1 + fOff, wt_bf, C_, DFF_);
    gemm64<2><<<dim3(32, 32, 1), 256, 0, stream>>>(a_bf, wt_bf,
        b1 + l*DFF_, nullptr, nullptr, mid_bf, nullptr, nullptr, M_, DFF_, C_);
    // FFN2, split-K=4 -> partials, then reduce(+b2, +resid in place)
    transpose_bf<<<dim3(32, 128), 256, 0, stream>>>(W2 + fOff, wt_bf, DFF_, C_);
    gemm64<3><<<dim3(8, 32, 4), 256, 0, stream>>>(mid_bf, wt_bf,
        nullptr, nullptr, nullptr, part, nullptr, nullptr, M_, C_, DFF_);
    reduce_k<4><<<(M_*C_/4)/256, 256, 0, stream>>>(h, b2 + l*C_, part);
  }
  // final LN -> f32 out
  ln_k<1><<<M_, 256, 0, stream>>>(h, lnfs, lnfb, d_out);
}